// Round 1
// baseline (1226.745 us; speedup 1.0000x reference)
//
#include <hip/hip_runtime.h>
#include <math.h>

#define D 256
#define V 10000
#define BB 16
#define NN 22
#define CF 400
#define CR 120
#define CA 48
#define NEGV -1000000000.0f

// ---------------- root scores: log_softmax(root_mask + root_w + root_b) ----------------
__global__ void k_root(const float* __restrict__ root_w, const float* __restrict__ root_b,
                       const float* __restrict__ root_mask, float* __restrict__ root_scores) {
  __shared__ float red[512];
  int t = threadIdx.x;
  float x = (t < CF) ? (root_mask[t] + root_w[t] + root_b[t]) : -INFINITY;
  red[t] = x; __syncthreads();
  for (int off = 256; off; off >>= 1) { if (t < off) red[t] = fmaxf(red[t], red[t + off]); __syncthreads(); }
  float m = red[0]; __syncthreads();
  red[t] = (t < CF) ? __expf(x - m) : 0.f; __syncthreads();
  for (int off = 256; off; off >>= 1) { if (t < off) red[t] += red[t + off]; __syncthreads(); }
  float z = m + __logf(red[0]);
  if (t < CF) root_scores[t] = x - z;
}

// ---------------- MLP: h = nt_emb@W1+b1; 2 residual blocks; split_scores = log_softmax(h@Wo+bo) ----
__global__ void k_mlp(const float* __restrict__ nt_emb, const float* __restrict__ W1,
                      const float* __restrict__ b1, const float* __restrict__ resW,
                      const float* __restrict__ resb, const float* __restrict__ Wo,
                      const float* __restrict__ bo, float* __restrict__ split_scores) {
  __shared__ float xs[4][D];
  __shared__ float hs[4][D];
  __shared__ float ts[4][D];
  __shared__ float red0[256], red1[256];
  int t = threadIdx.x;
  int f0 = blockIdx.x * 4;
  for (int ri = 0; ri < 4; ri++) xs[ri][t] = nt_emb[(f0 + ri) * D + t];
  __syncthreads();
  float acc[4];
  for (int ri = 0; ri < 4; ri++) acc[ri] = b1[t];
  for (int d = 0; d < D; d++) {
    float wv = W1[d * D + t];
    for (int ri = 0; ri < 4; ri++) acc[ri] += xs[ri][d] * wv;
  }
  for (int ri = 0; ri < 4; ri++) hs[ri][t] = acc[ri];
  __syncthreads();
  for (int i = 0; i < 2; i++) {
    for (int ri = 0; ri < 4; ri++) acc[ri] = resb[(i * 2 + 0) * D + t];
    for (int d = 0; d < D; d++) {
      float wv = resW[((i * 2 + 0) * D + d) * D + t];
      for (int ri = 0; ri < 4; ri++) acc[ri] += hs[ri][d] * wv;
    }
    for (int ri = 0; ri < 4; ri++) ts[ri][t] = fmaxf(acc[ri], 0.f);
    __syncthreads();
    for (int ri = 0; ri < 4; ri++) acc[ri] = resb[(i * 2 + 1) * D + t];
    for (int d = 0; d < D; d++) {
      float wv = resW[((i * 2 + 1) * D + d) * D + t];
      for (int ri = 0; ri < 4; ri++) acc[ri] += ts[ri][d] * wv;
    }
    __syncthreads();
    for (int ri = 0; ri < 4; ri++) hs[ri][t] = fmaxf(acc[ri], 0.f) + hs[ri][t];
    __syncthreads();
  }
  for (int ri = 0; ri < 4; ri++) {
    red0[t] = hs[ri][t] * Wo[t * 2 + 0];
    red1[t] = hs[ri][t] * Wo[t * 2 + 1];
    __syncthreads();
    for (int off = 128; off; off >>= 1) {
      if (t < off) { red0[t] += red0[t + off]; red1[t] += red1[t + off]; }
      __syncthreads();
    }
    if (t == 0) {
      float s0 = red0[0] + bo[0], s1 = red1[0] + bo[1];
      float m = fmaxf(s0, s1);
      float z = m + __logf(__expf(s0 - m) + __expf(s1 - m));
      split_scores[(f0 + ri) * 2 + 0] = s0 - z;
      split_scores[(f0 + ri) * 2 + 1] = s1 - z;
    }
    __syncthreads();
  }
}

// ---------------- gL/gR from rule_W (fake_emb is identity) ----------------
__global__ void k_glgr(const float* __restrict__ rule_W, const float* __restrict__ rule_b,
                       const float* __restrict__ split_scores,
                       float* __restrict__ gL, float* __restrict__ gR) {
  __shared__ float red[128];
  int r = blockIdx.x;
  int t = threadIdx.x;
  float x = (t < 96) ? (rule_W[t * CR + r] + rule_b[t]) : -INFINITY;
  red[t] = x; __syncthreads();
  for (int off = 64; off; off >>= 1) { if (t < off) red[t] = fmaxf(red[t], red[t + off]); __syncthreads(); }
  float m = red[0]; __syncthreads();
  red[t] = (t < 96) ? __expf(x - m) : 0.f; __syncthreads();
  for (int off = 64; off; off >>= 1) { if (t < off) red[t] += red[t + off]; __syncthreads(); }
  float z = m + __logf(red[0]);
  float s0 = split_scores[r * 2 + 0];
  if (t < CA) gL[r * CA + t] = (x - z) + s0;
  else if (t < 96) gR[r * CA + (t - CA)] = (x - z) + s0;
}

// ---------------- emission: per-row partial sum of exp(logits) over a column tile ----------------
#define RT 8
#define CTILE 1000
__global__ void k_emit_partial(const float* __restrict__ nt_emb, const float* __restrict__ emit_W,
                               const float* __restrict__ emit_b, float* __restrict__ partial) {
  __shared__ float xs[RT][D];
  __shared__ float red[256];
  int t = threadIdx.x;
  int f0 = blockIdx.x * RT;
  int c0 = blockIdx.y * CTILE;
  for (int ri = 0; ri < RT; ri++) xs[ri][t] = nt_emb[(f0 + ri) * D + t];
  __syncthreads();
  float psum[RT];
  for (int ri = 0; ri < RT; ri++) psum[ri] = 0.f;
  for (int cc = 0; cc < 4; cc++) {
    int v = c0 + cc * 256 + t;
    if (v < c0 + CTILE && v < V) {
      float acc[RT];
      for (int ri = 0; ri < RT; ri++) acc[ri] = 0.f;
      for (int d = 0; d < D; d++) {
        float wv = emit_W[d * V + v];
        for (int ri = 0; ri < RT; ri++) acc[ri] += xs[ri][d] * wv;
      }
      float eb = emit_b[v];
      for (int ri = 0; ri < RT; ri++) psum[ri] += __expf(acc[ri] + eb);
    }
  }
  for (int ri = 0; ri < RT; ri++) {
    red[t] = psum[ri]; __syncthreads();
    for (int off = 128; off; off >>= 1) { if (t < off) red[t] += red[t + off]; __syncthreads(); }
    if (t == 0) partial[(f0 + ri) * 16 + blockIdx.y] = red[0];
    __syncthreads();
  }
}

__global__ void k_logz(const float* __restrict__ partial, float* __restrict__ logZ) {
  int t = blockIdx.x * blockDim.x + threadIdx.x;
  if (t < CF) {
    float s = 0.f;
    for (int ct = 0; ct < 10; ct++) s += partial[t * 16 + ct];
    logZ[t] = __logf(s);
  }
}

// ---------------- terminal scores -> beta diagonal ----------------
__global__ void k_term(const float* __restrict__ nt_emb, const float* __restrict__ emit_W,
                       const float* __restrict__ emit_b, const int* __restrict__ words,
                       const float* __restrict__ split_scores, const float* __restrict__ logZ,
                       float* __restrict__ beta) {
  __shared__ float wcol[D];
  int blk = blockIdx.x;
  int b = blk / NN, n = blk % NN;
  int t = threadIdx.x;
  int w = words[b * NN + n];
  wcol[t] = emit_W[t * V + w];
  __syncthreads();
  float eb = emit_b[w];
  for (int f = t; f < CF; f += 256) {
    const float4* xp = (const float4*)(nt_emb + (size_t)f * D);
    float acc = 0.f;
    for (int d4 = 0; d4 < D / 4; d4++) {
      float4 xv = xp[d4];
      acc += xv.x * wcol[4 * d4] + xv.y * wcol[4 * d4 + 1] + xv.z * wcol[4 * d4 + 2] + xv.w * wcol[4 * d4 + 3];
    }
    float val = split_scores[f * 2 + 1] + (acc + eb) - logZ[f];
    beta[(((size_t)n * NN + n) * BB + b) * CF + f] = val;
  }
}

// ---------------- CKY step for width w ----------------
__global__ void k_cky(const float* __restrict__ gL, const float* __restrict__ gR,
                      const int* __restrict__ lf, const int* __restrict__ rf,
                      float* __restrict__ beta, int w) {
  __shared__ float ldsL[21 * CF];
  __shared__ float ldsR[21 * CF];
  __shared__ float redm[256], reds[256];
  int t = threadIdx.x;
  int s = blockIdx.x / BB;
  int b = blockIdx.x % BB;
  int i = s, j = s + w - 1;
  int wm1 = w - 1;
  int tot = wm1 * CF;
  for (int idx = t; idx < tot; idx += 256) {
    int km = idx / CF;
    int f = idx - km * CF;
    ldsL[idx] = beta[(((size_t)i * NN + (i + km)) * BB + b) * CF + f];
    ldsR[idx] = beta[(((size_t)(i + km + 1) * NN + j) * BB + b) * CF + f];
  }
  __syncthreads();
  float m = -INFINITY, ssum = 0.f;
  if (t < 240) {
    int r = t % CR;
    int a0 = (t / CR) * 24;
    float gl[24], gr[24];
    int lfi[24], rfi[24];
#pragma unroll
    for (int aa = 0; aa < 24; aa++) {
      int a = a0 + aa;
      gl[aa] = gL[r * CA + a];
      gr[aa] = gR[r * CA + a];
      lfi[aa] = lf[r * CA + a];
      rfi[aa] = rf[r * CA + a];
    }
    for (int km = 0; km < wm1; km++) {
      const float* L = &ldsL[km * CF];
      const float* R = &ldsR[km * CF];
#pragma unroll
      for (int aa = 0; aa < 24; aa++) {
        int a = a0 + aa;
        float tl = gl[aa] + L[a] + R[rfi[aa]];
        float tr = gr[aa] + L[lfi[aa]] + R[a];
        m = fmaxf(m, fmaxf(tl, tr));
      }
    }
    for (int km = 0; km < wm1; km++) {
      const float* L = &ldsL[km * CF];
      const float* R = &ldsR[km * CF];
#pragma unroll
      for (int aa = 0; aa < 24; aa++) {
        int a = a0 + aa;
        float tl = gl[aa] + L[a] + R[rfi[aa]];
        float tr = gr[aa] + L[lfi[aa]] + R[a];
        ssum += __expf(tl - m) + __expf(tr - m);
      }
    }
  }
  redm[t] = m;
  reds[t] = ssum;
  __syncthreads();
  if (t < CR) {
    float m1 = redm[t], s1 = reds[t], m2 = redm[t + CR], s2 = reds[t + CR];
    float M = fmaxf(m1, m2);
    float val = M + __logf(s1 * __expf(m1 - M) + s2 * __expf(m2 - M));
    beta[(((size_t)i * NN + j) * BB + b) * CF + t] = val;
  }
  for (int f = CR + t; f < CF; f += 256) {
    beta[(((size_t)i * NN + j) * BB + b) * CF + f] = NEGV;
  }
}

// ---------------- final: out[b] = -LSE_f(root_scores[f] + beta[0][N-1][b][f]) ----------------
__global__ void k_final(const float* __restrict__ root_scores, const float* __restrict__ beta,
                        float* __restrict__ out) {
  __shared__ float red[256];
  int b = blockIdx.x;
  int t = threadIdx.x;
  const float* row = &beta[(((size_t)0 * NN + (NN - 1)) * BB + b) * CF];
  float x1 = (t < CF) ? root_scores[t] + row[t] : -INFINITY;
  float x2 = (t + 256 < CF) ? root_scores[t + 256] + row[t + 256] : -INFINITY;
  float mx = fmaxf(x1, x2);
  red[t] = mx; __syncthreads();
  for (int off = 128; off; off >>= 1) { if (t < off) red[t] = fmaxf(red[t], red[t + off]); __syncthreads(); }
  float M = red[0]; __syncthreads();
  float e = ((t < CF) ? __expf(x1 - M) : 0.f) + ((t + 256 < CF) ? __expf(x2 - M) : 0.f);
  red[t] = e; __syncthreads();
  for (int off = 128; off; off >>= 1) { if (t < off) red[t] += red[t + off]; __syncthreads(); }
  if (t == 0) out[b] = -(M + __logf(red[0]));
}

extern "C" void kernel_launch(void* const* d_in, const int* in_sizes, int n_in,
                              void* d_out, int out_size, void* d_ws, size_t ws_size,
                              hipStream_t stream) {
  const float* nt_emb   = (const float*)d_in[1];
  const float* rule_W   = (const float*)d_in[2];
  const float* rule_b   = (const float*)d_in[3];
  const float* root_w   = (const float*)d_in[4];
  const float* root_b   = (const float*)d_in[5];
  const float* root_mask= (const float*)d_in[6];
  const float* split_W1 = (const float*)d_in[7];
  const float* split_b1 = (const float*)d_in[8];
  const float* res_W    = (const float*)d_in[9];
  const float* res_b    = (const float*)d_in[10];
  const float* split_Wo = (const float*)d_in[11];
  const float* split_bo = (const float*)d_in[12];
  const float* emit_W   = (const float*)d_in[13];
  const float* emit_b   = (const float*)d_in[14];
  const int*   words    = (const int*)d_in[15];
  const int*   lfunc    = (const int*)d_in[16];
  const int*   rfunc    = (const int*)d_in[17];

  float* ws = (float*)d_ws;
  float* beta         = ws;                       // 22*22*16*400 = 3,097,600
  float* root_scores  = ws + 3097600;             // 400
  float* split_scores = root_scores + CF;         // 800
  float* gLbuf        = split_scores + 2 * CF;    // 5760
  float* gRbuf        = gLbuf + CR * CA;          // 5760
  float* logZ         = gRbuf + CR * CA;          // 400
  float* partial      = logZ + CF;                // 400*16

  hipLaunchKernelGGL(k_root, dim3(1), dim3(512), 0, stream, root_w, root_b, root_mask, root_scores);
  hipLaunchKernelGGL(k_mlp, dim3(100), dim3(256), 0, stream, nt_emb, split_W1, split_b1,
                     res_W, res_b, split_Wo, split_bo, split_scores);
  hipLaunchKernelGGL(k_glgr, dim3(CR), dim3(128), 0, stream, rule_W, rule_b, split_scores, gLbuf, gRbuf);
  hipLaunchKernelGGL(k_emit_partial, dim3(50, 10), dim3(256), 0, stream, nt_emb, emit_W, emit_b, partial);
  hipLaunchKernelGGL(k_logz, dim3(2), dim3(256), 0, stream, partial, logZ);
  hipLaunchKernelGGL(k_term, dim3(BB * NN), dim3(256), 0, stream, nt_emb, emit_W, emit_b,
                     words, split_scores, logZ, beta);
  for (int w = 2; w <= NN; w++) {
    int S = NN - w + 1;
    hipLaunchKernelGGL(k_cky, dim3(S * BB), dim3(256), 0, stream, gLbuf, gRbuf, lfunc, rfunc, beta, w);
  }
  hipLaunchKernelGGL(k_final, dim3(BB), dim3(256), 0, stream, root_scores, beta, (float*)d_out);
}

// Round 2
// 817.714 us; speedup vs baseline: 1.5002x; 1.5002x over previous
//
#include <hip/hip_runtime.h>
#include <math.h>

#define D 256
#define V 10000
#define BB 16
#define NN 22
#define CF 400
#define CR 120
#define CA 48
#define NEGV -1000000000.0f

// ---------------- root scores: log_softmax(root_mask + root_w + root_b) ----------------
__global__ void k_root(const float* __restrict__ root_w, const float* __restrict__ root_b,
                       const float* __restrict__ root_mask, float* __restrict__ root_scores) {
  __shared__ float red[512];
  int t = threadIdx.x;
  float x = (t < CF) ? (root_mask[t] + root_w[t] + root_b[t]) : -INFINITY;
  red[t] = x; __syncthreads();
  for (int off = 256; off; off >>= 1) { if (t < off) red[t] = fmaxf(red[t], red[t + off]); __syncthreads(); }
  float m = red[0]; __syncthreads();
  red[t] = (t < CF) ? __expf(x - m) : 0.f; __syncthreads();
  for (int off = 256; off; off >>= 1) { if (t < off) red[t] += red[t + off]; __syncthreads(); }
  float z = m + __logf(red[0]);
  if (t < CF) root_scores[t] = x - z;
}

// ---------------- MLP: h = nt_emb@W1+b1; 2 residual blocks; split_scores = log_softmax(h@Wo+bo) ----
__global__ void k_mlp(const float* __restrict__ nt_emb, const float* __restrict__ W1,
                      const float* __restrict__ b1, const float* __restrict__ resW,
                      const float* __restrict__ resb, const float* __restrict__ Wo,
                      const float* __restrict__ bo, float* __restrict__ split_scores) {
  __shared__ float xs[4][D];
  __shared__ float hs[4][D];
  __shared__ float ts[4][D];
  __shared__ float red0[256], red1[256];
  int t = threadIdx.x;
  int f0 = blockIdx.x * 4;
  for (int ri = 0; ri < 4; ri++) xs[ri][t] = nt_emb[(f0 + ri) * D + t];
  __syncthreads();
  float acc[4];
  for (int ri = 0; ri < 4; ri++) acc[ri] = b1[t];
  for (int d = 0; d < D; d++) {
    float wv = W1[d * D + t];
    for (int ri = 0; ri < 4; ri++) acc[ri] += xs[ri][d] * wv;
  }
  for (int ri = 0; ri < 4; ri++) hs[ri][t] = acc[ri];
  __syncthreads();
  for (int i = 0; i < 2; i++) {
    for (int ri = 0; ri < 4; ri++) acc[ri] = resb[(i * 2 + 0) * D + t];
    for (int d = 0; d < D; d++) {
      float wv = resW[((i * 2 + 0) * D + d) * D + t];
      for (int ri = 0; ri < 4; ri++) acc[ri] += hs[ri][d] * wv;
    }
    for (int ri = 0; ri < 4; ri++) ts[ri][t] = fmaxf(acc[ri], 0.f);
    __syncthreads();
    for (int ri = 0; ri < 4; ri++) acc[ri] = resb[(i * 2 + 1) * D + t];
    for (int d = 0; d < D; d++) {
      float wv = resW[((i * 2 + 1) * D + d) * D + t];
      for (int ri = 0; ri < 4; ri++) acc[ri] += ts[ri][d] * wv;
    }
    __syncthreads();
    for (int ri = 0; ri < 4; ri++) hs[ri][t] = fmaxf(acc[ri], 0.f) + hs[ri][t];
    __syncthreads();
  }
  for (int ri = 0; ri < 4; ri++) {
    red0[t] = hs[ri][t] * Wo[t * 2 + 0];
    red1[t] = hs[ri][t] * Wo[t * 2 + 1];
    __syncthreads();
    for (int off = 128; off; off >>= 1) {
      if (t < off) { red0[t] += red0[t + off]; red1[t] += red1[t + off]; }
      __syncthreads();
    }
    if (t == 0) {
      float s0 = red0[0] + bo[0], s1 = red1[0] + bo[1];
      float m = fmaxf(s0, s1);
      float z = m + __logf(__expf(s0 - m) + __expf(s1 - m));
      split_scores[(f0 + ri) * 2 + 0] = s0 - z;
      split_scores[(f0 + ri) * 2 + 1] = s1 - z;
    }
    __syncthreads();
  }
}

// ---------------- egL/egR = exp(rule log-softmax + split0)  (fake_emb is identity) ----------------
__global__ void k_glgr(const float* __restrict__ rule_W, const float* __restrict__ rule_b,
                       const float* __restrict__ split_scores,
                       float* __restrict__ egL, float* __restrict__ egR) {
  __shared__ float red[128];
  int r = blockIdx.x;
  int t = threadIdx.x;
  float x = (t < 96) ? (rule_W[t * CR + r] + rule_b[t]) : -INFINITY;
  red[t] = x; __syncthreads();
  for (int off = 64; off; off >>= 1) { if (t < off) red[t] = fmaxf(red[t], red[t + off]); __syncthreads(); }
  float m = red[0]; __syncthreads();
  red[t] = (t < 96) ? __expf(x - m) : 0.f; __syncthreads();
  for (int off = 64; off; off >>= 1) { if (t < off) red[t] += red[t + off]; __syncthreads(); }
  float z = m + __logf(red[0]);
  float s0 = split_scores[r * 2 + 0];
  if (t < CA) egL[r * CA + t] = __expf((x - z) + s0);
  else if (t < 96) egR[r * CA + (t - CA)] = __expf((x - z) + s0);
}

// ---------------- emission: per-row partial sum of exp(logits), float4 over v ----------------
#define RT 8
__global__ void k_emit_partial(const float* __restrict__ nt_emb, const float* __restrict__ emit_W,
                               const float* __restrict__ emit_b, float* __restrict__ partial) {
  __shared__ float xs[RT][D];
  __shared__ float ldsw[RT][4];
  int t = threadIdx.x;
  int f0 = blockIdx.x * RT;
  int v0 = blockIdx.y * 1024 + t * 4;
  for (int ri = 0; ri < RT; ri++) xs[ri][t] = nt_emb[(f0 + ri) * D + t];
  __syncthreads();
  float psum[RT];
  for (int ri = 0; ri < RT; ri++) psum[ri] = 0.f;
  if (v0 < V) {
    float acc[RT][4];
    for (int ri = 0; ri < RT; ri++)
      for (int j = 0; j < 4; j++) acc[ri][j] = 0.f;
    for (int d4 = 0; d4 < D / 4; d4++) {
      float4 w0 = *(const float4*)(emit_W + (size_t)(4 * d4 + 0) * V + v0);
      float4 w1 = *(const float4*)(emit_W + (size_t)(4 * d4 + 1) * V + v0);
      float4 w2 = *(const float4*)(emit_W + (size_t)(4 * d4 + 2) * V + v0);
      float4 w3 = *(const float4*)(emit_W + (size_t)(4 * d4 + 3) * V + v0);
#pragma unroll
      for (int ri = 0; ri < RT; ri++) {
        float4 xv = *(const float4*)(&xs[ri][4 * d4]);
        acc[ri][0] += xv.x * w0.x + xv.y * w1.x + xv.z * w2.x + xv.w * w3.x;
        acc[ri][1] += xv.x * w0.y + xv.y * w1.y + xv.z * w2.y + xv.w * w3.y;
        acc[ri][2] += xv.x * w0.z + xv.y * w1.z + xv.z * w2.z + xv.w * w3.z;
        acc[ri][3] += xv.x * w0.w + xv.y * w1.w + xv.z * w2.w + xv.w * w3.w;
      }
    }
    float4 eb = *(const float4*)(emit_b + v0);
    for (int ri = 0; ri < RT; ri++)
      psum[ri] = __expf(acc[ri][0] + eb.x) + __expf(acc[ri][1] + eb.y) +
                 __expf(acc[ri][2] + eb.z) + __expf(acc[ri][3] + eb.w);
  }
  int lane = t & 63, wid = t >> 6;
  for (int ri = 0; ri < RT; ri++) {
    float v = psum[ri];
    for (int off = 32; off; off >>= 1) v += __shfl_down(v, off, 64);
    if (lane == 0) ldsw[ri][wid] = v;
  }
  __syncthreads();
  if (t < RT) {
    float s = ldsw[t][0] + ldsw[t][1] + ldsw[t][2] + ldsw[t][3];
    partial[(f0 + t) * 16 + blockIdx.y] = s;
  }
}

__global__ void k_logz(const float* __restrict__ partial, float* __restrict__ logZ) {
  int t = blockIdx.x * blockDim.x + threadIdx.x;
  if (t < CF) {
    float s = 0.f;
    for (int ct = 0; ct < 10; ct++) s += partial[t * 16 + ct];
    logZ[t] = __logf(s);
  }
}

// ---------------- terminal scores -> beta diagonal (+ row max) ----------------
__global__ void k_term(const float* __restrict__ nt_emb, const float* __restrict__ emit_W,
                       const float* __restrict__ emit_b, const int* __restrict__ words,
                       const float* __restrict__ split_scores, const float* __restrict__ logZ,
                       float* __restrict__ beta, float* __restrict__ bmax) {
  __shared__ float wcol[D];
  __shared__ float red[256];
  int blk = blockIdx.x;
  int b = blk / NN, n = blk % NN;
  int t = threadIdx.x;
  int w = words[b * NN + n];
  wcol[t] = emit_W[t * V + w];
  __syncthreads();
  float eb = emit_b[w];
  float vmax = -INFINITY;
  for (int f = t; f < CF; f += 256) {
    const float4* xp = (const float4*)(nt_emb + (size_t)f * D);
    float acc = 0.f;
    for (int d4 = 0; d4 < D / 4; d4++) {
      float4 xv = xp[d4];
      acc += xv.x * wcol[4 * d4] + xv.y * wcol[4 * d4 + 1] + xv.z * wcol[4 * d4 + 2] + xv.w * wcol[4 * d4 + 3];
    }
    float val = split_scores[f * 2 + 1] + (acc + eb) - logZ[f];
    beta[(((size_t)n * NN + n) * BB + b) * CF + f] = val;
    vmax = fmaxf(vmax, val);
  }
  red[t] = vmax; __syncthreads();
  for (int off = 128; off; off >>= 1) { if (t < off) red[t] = fmaxf(red[t], red[t + off]); __syncthreads(); }
  if (t == 0) bmax[((size_t)n * NN + n) * BB + b] = red[0];
}

// ---------------- CKY step for width w (sum-domain, factored LSE) ----------------
__global__ void k_cky(const float* __restrict__ egL, const float* __restrict__ egR,
                      const int* __restrict__ lf, const int* __restrict__ rf,
                      float* __restrict__ beta, float* __restrict__ bmax, int w) {
  __shared__ float EL[21 * CF];
  __shared__ float ER[21 * CF];
  __shared__ float mR[21];
  __shared__ float sM[21];
  __shared__ float red[256];
  __shared__ float Msh;
  int t = threadIdx.x;
  int s = blockIdx.x / BB;
  int b = blockIdx.x % BB;
  int i = s, j = s + w - 1;
  int wm1 = w - 1;
  if (t < wm1) {
    float ml = bmax[((size_t)i * NN + (i + t)) * BB + b];
    float mr = bmax[((size_t)(i + t + 1) * NN + j) * BB + b];
    mR[t] = mr;
    sM[t] = ml + mr;
  }
  __syncthreads();
  if (t == 0) {
    float M = sM[0];
    for (int k = 1; k < wm1; k++) M = fmaxf(M, sM[k]);
    Msh = M;
  }
  __syncthreads();
  float M = Msh;
  int tot = wm1 * CF;
  for (int idx = t; idx < tot; idx += 256) {
    int km = idx / CF;
    int f = idx - km * CF;
    float lv = beta[(((size_t)i * NN + (i + km)) * BB + b) * CF + f];
    float rv = beta[(((size_t)(i + km + 1) * NN + j) * BB + b) * CF + f];
    EL[idx] = __expf(lv + mR[km] - M);
    ER[idx] = __expf(rv - mR[km]);
  }
  __syncthreads();
  float acc = 0.f;
  if (t < 240) {
    int r = t % CR;
    int a0 = (t / CR) * 24;
#pragma unroll 4
    for (int aa = 0; aa < 24; aa++) {
      int a = a0 + aa;
      float gl = egL[r * CA + a];
      float gr = egR[r * CA + a];
      int fL = rf[r * CA + a];
      int fR = lf[r * CA + a];
      float dA = 0.f, dB = 0.f;
      for (int km = 0; km < wm1; km++) {
        dA += EL[km * CF + a] * ER[km * CF + fL];
        dB += EL[km * CF + fR] * ER[km * CF + a];
      }
      acc += gl * dA + gr * dB;
    }
  }
  red[t] = acc;
  __syncthreads();
  float val = -INFINITY;
  if (t < CR) {
    float sum = red[t] + red[t + CR];
    val = __logf(fmaxf(sum, 1e-45f)) + M;
    beta[(((size_t)i * NN + j) * BB + b) * CF + t] = val;
  }
  __syncthreads();
  red[t] = val;
  __syncthreads();
  for (int off = 128; off; off >>= 1) { if (t < off) red[t] = fmaxf(red[t], red[t + off]); __syncthreads(); }
  if (t == 0) bmax[((size_t)i * NN + j) * BB + b] = red[0];
  for (int f = CR + t; f < CF; f += 256) {
    beta[(((size_t)i * NN + j) * BB + b) * CF + f] = NEGV;
  }
}

// ---------------- final: out[b] = -LSE_f(root_scores[f] + beta[0][N-1][b][f]) ----------------
__global__ void k_final(const float* __restrict__ root_scores, const float* __restrict__ beta,
                        float* __restrict__ out) {
  __shared__ float red[256];
  int b = blockIdx.x;
  int t = threadIdx.x;
  const float* row = &beta[(((size_t)0 * NN + (NN - 1)) * BB + b) * CF];
  float x1 = (t < CF) ? root_scores[t] + row[t] : -INFINITY;
  float x2 = (t + 256 < CF) ? root_scores[t + 256] + row[t + 256] : -INFINITY;
  float mx = fmaxf(x1, x2);
  red[t] = mx; __syncthreads();
  for (int off = 128; off; off >>= 1) { if (t < off) red[t] = fmaxf(red[t], red[t + off]); __syncthreads(); }
  float M = red[0]; __syncthreads();
  float e = ((t < CF) ? __expf(x1 - M) : 0.f) + ((t + 256 < CF) ? __expf(x2 - M) : 0.f);
  red[t] = e; __syncthreads();
  for (int off = 128; off; off >>= 1) { if (t < off) red[t] += red[t + off]; __syncthreads(); }
  if (t == 0) out[b] = -(M + __logf(red[0]));
}

extern "C" void kernel_launch(void* const* d_in, const int* in_sizes, int n_in,
                              void* d_out, int out_size, void* d_ws, size_t ws_size,
                              hipStream_t stream) {
  const float* nt_emb   = (const float*)d_in[1];
  const float* rule_W   = (const float*)d_in[2];
  const float* rule_b   = (const float*)d_in[3];
  const float* root_w   = (const float*)d_in[4];
  const float* root_b   = (const float*)d_in[5];
  const float* root_mask= (const float*)d_in[6];
  const float* split_W1 = (const float*)d_in[7];
  const float* split_b1 = (const float*)d_in[8];
  const float* res_W    = (const float*)d_in[9];
  const float* res_b    = (const float*)d_in[10];
  const float* split_Wo = (const float*)d_in[11];
  const float* split_bo = (const float*)d_in[12];
  const float* emit_W   = (const float*)d_in[13];
  const float* emit_b   = (const float*)d_in[14];
  const int*   words    = (const int*)d_in[15];
  const int*   lfunc    = (const int*)d_in[16];
  const int*   rfunc    = (const int*)d_in[17];

  float* ws = (float*)d_ws;
  float* beta         = ws;                       // 22*22*16*400 = 3,097,600
  float* root_scores  = ws + 3097600;             // 400
  float* split_scores = root_scores + CF;         // 800
  float* egLbuf       = split_scores + 2 * CF;    // 5760
  float* egRbuf       = egLbuf + CR * CA;         // 5760
  float* logZ         = egRbuf + CR * CA;         // 400
  float* partial      = logZ + CF;                // 6400
  float* bmaxbuf      = partial + CF * 16;        // 22*22*16 = 7744

  hipLaunchKernelGGL(k_root, dim3(1), dim3(512), 0, stream, root_w, root_b, root_mask, root_scores);
  hipLaunchKernelGGL(k_mlp, dim3(100), dim3(256), 0, stream, nt_emb, split_W1, split_b1,
                     res_W, res_b, split_Wo, split_bo, split_scores);
  hipLaunchKernelGGL(k_glgr, dim3(CR), dim3(128), 0, stream, rule_W, rule_b, split_scores, egLbuf, egRbuf);
  hipLaunchKernelGGL(k_emit_partial, dim3(50, 10), dim3(256), 0, stream, nt_emb, emit_W, emit_b, partial);
  hipLaunchKernelGGL(k_logz, dim3(2), dim3(256), 0, stream, partial, logZ);
  hipLaunchKernelGGL(k_term, dim3(BB * NN), dim3(256), 0, stream, nt_emb, emit_W, emit_b,
                     words, split_scores, logZ, beta, bmaxbuf);
  for (int w = 2; w <= NN; w++) {
    int S = NN - w + 1;
    hipLaunchKernelGGL(k_cky, dim3(S * BB), dim3(256), 0, stream, egLbuf, egRbuf, lfunc, rfunc,
                       beta, bmaxbuf, w);
  }
  hipLaunchKernelGGL(k_final, dim3(BB), dim3(256), 0, stream, root_scores, beta, (float*)d_out);
}